// Round 18
// baseline (191.085 us; speedup 1.0000x reference)
//
#include <hip/hip_runtime.h>
#include <hip/hip_bf16.h>

#define LL 9216            // 96*96
#define TOT 36864          // 4*LL
#define CHK 144
#define NSEG 144
#define EPS_N 5e-5f

typedef __bf16 bf16x8 __attribute__((ext_vector_type(8)));
typedef float f32x4 __attribute__((ext_vector_type(4)));

__device__ __forceinline__ float dot4(float4 a, float4 b) {
    return a.x*b.x + a.y*b.y + a.z*b.z + a.w*b.w;
}
__device__ __forceinline__ unsigned short f2bf(float f) {
    __hip_bfloat16 h = __float2bfloat16(f);
    return *reinterpret_cast<unsigned short*>(&h);
}
__device__ __forceinline__ float bf2f(unsigned short u) {
    return __uint_as_float(((unsigned int)u) << 16);
}

// ---------------- K0: weight prep (extracted so k_conv2 can depend on it) -------
__global__ __launch_bounds__(256) void k_wprep(
    const float* __restrict__ fc1w, const float* __restrict__ fc2w,
    const float* __restrict__ wa, const float* __restrict__ wf,
    unsigned short* __restrict__ w1bf, unsigned short* __restrict__ w2bf,
    unsigned short* __restrict__ wpack)
{
    int i = blockIdx.x * 256 + threadIdx.x;
    if (i < 144 * 64) w1bf[i] = f2bf(fc1w[i]);
    if (i < 144 * 160) {
        int r = i / 160, c = i - r * 160;
        w2bf[i] = (c < 144) ? f2bf(fc2w[r * 144 + c]) : 0;
    }
    if (i < 128 * 576) {
        int o = i / 576, kk = i - o * 576;
        int dydx = kk >> 6, c = kk & 63;
        const float* src = (o < 64) ? wa : wf;
        wpack[i] = f2bf(src[(o & 63) * 576 + c * 9 + dydx]);
    }
}

// ---------------- K1: merged convs — front-conv ∥ convbf-conv --------------------
// FINAL lock-in (verified 190.1us x2: R12/R17). Hot-loop edits (R13/R14)
// regressed via co-compile codegen perturbation; structural fusion (R16) was
// net-neutral. This source has the proven-good allocation for every kernel.
__global__ __launch_bounds__(256) void k_conv2(
    const float* __restrict__ x, const float* __restrict__ wm,
    const float* __restrict__ bm, const float* __restrict__ rot,
    unsigned short* __restrict__ xeb, unsigned short* __restrict__ xnb,
    unsigned char* __restrict__ codes,
    const unsigned short* __restrict__ wpack,
    const float* __restrict__ ba, const float* __restrict__ bfb,
    const unsigned short* __restrict__ w1bf, const float* __restrict__ fc1_b,
    const unsigned short* __restrict__ w2bf, const float* __restrict__ fc2_b,
    unsigned short* __restrict__ yeb, unsigned short* __restrict__ re2b)
{
    __shared__ __align__(16) char smem[47104];   // union of both layouts
    int tid = threadIdx.x;
    int b7 = blockIdx.x % 7, bq = blockIdx.x / 7;

    if (b7 < 3) {
        // ================= front-conv personality (b = 0..287) =================
        float* xl   = (float*)smem;               // [64][10][10]  25600 B
        float* rotT = (float*)(smem + 25600);     // [256][16]     16384 B
        float* xsp  = (float*)(smem + 41984);     // [64][20]       5120 B
        int b = bq * 3 + b7;
        int n = b / 144, tile = b % 144;
        int ty0 = (tile / 12) * 8, tx0 = (tile % 12) * 8;
        for (int li = tid; li < 6400; li += 256) {
            int c = li / 100, s = li % 100;
            int yy = s / 10, xx = s % 10;
            int gy = ty0 + yy - 1, gx = tx0 + xx - 1;
            float v = 0.f;
            if ((unsigned)gy < 96u && (unsigned)gx < 96u)
                v = x[((n * 64 + c) * 96 + gy) * 96 + gx];
            xl[li] = v;
        }
        for (int e = tid; e < 4096; e += 256) {
            int f = e >> 8, r = e & 255;
            rotT[r * 16 + f] = rot[f * 256 + r];   // rot is (16,4,64)
        }
        __syncthreads();
        int p = tid & 63, og = tid >> 6;
        int row = p >> 3, col = p & 7;
        int ogs = __builtin_amdgcn_readfirstlane(og);   // wave-uniform -> s_load
        const float* wb = wm + (size_t)ogs * 4 * 576;
        float acc0 = 0.f, acc1 = 0.f, acc2 = 0.f, acc3 = 0.f;
        for (int c = 0; c < 64; ++c) {
            float xp[9];
            int base = c * 100 + row * 10 + col;
            #pragma unroll
            for (int dy = 0; dy < 3; ++dy)
                #pragma unroll
                for (int dx = 0; dx < 3; ++dx)
                    xp[dy * 3 + dx] = xl[base + dy * 10 + dx];
            const float* w0 = wb + c * 9;
            #pragma unroll
            for (int u = 0; u < 9; ++u) {
                acc0 += w0[u]        * xp[u];
                acc1 += w0[576 + u]  * xp[u];
                acc2 += w0[1152 + u] * xp[u];
                acc3 += w0[1728 + u] * xp[u];
            }
        }
        int o = ogs * 4;
        float v0 = acc0 + bm[o + 0]; v0 = v0 > 0.f ? v0 : 0.f;
        float v1 = acc1 + bm[o + 1]; v1 = v1 > 0.f ? v1 : 0.f;
        float v2 = acc2 + bm[o + 2]; v2 = v2 > 0.f ? v2 : 0.f;
        float v3 = acc3 + bm[o + 3]; v3 = v3 > 0.f ? v3 : 0.f;
        size_t t = (size_t)n * LL + (ty0 + row) * 96 + tx0 + col;
        unsigned short pk[4] = {f2bf(v0), f2bf(v1), f2bf(v2), f2bf(v3)};
        *(uint2*)(xeb + t * 16 + o) = *(uint2*)pk;
        *(float4*)(xsp + p * 20 + o) = make_float4(v0, v1, v2, v3);
        __syncthreads();
        // ---- codes phase: thread = (pos = tid&63, h = tid>>6) ----
        int pos = tid & 63, h = tid >> 6;
        int prow = pos >> 3, pcol = pos & 7;
        size_t tc = (size_t)n * LL + (ty0 + prow) * 96 + tx0 + pcol;
        float4 q0 = *(float4*)(xsp + pos * 20 + 0);
        float4 q1 = *(float4*)(xsp + pos * 20 + 4);
        float4 q2 = *(float4*)(xsp + pos * 20 + 8);
        float4 q3 = *(float4*)(xsp + pos * 20 + 12);
        if (h == 0) {
            float nn = dot4(q0,q0) + dot4(q1,q1) + dot4(q2,q2) + dot4(q3,q3);
            float s = fmaxf(sqrtf(nn), EPS_N);
            float inv = 1.f / s;
            unsigned short pn[16];
            pn[0]=f2bf(q0.x*inv);  pn[1]=f2bf(q0.y*inv);  pn[2]=f2bf(q0.z*inv);  pn[3]=f2bf(q0.w*inv);
            pn[4]=f2bf(q1.x*inv);  pn[5]=f2bf(q1.y*inv);  pn[6]=f2bf(q1.z*inv);  pn[7]=f2bf(q1.w*inv);
            pn[8]=f2bf(q2.x*inv);  pn[9]=f2bf(q2.y*inv);  pn[10]=f2bf(q2.z*inv); pn[11]=f2bf(q2.w*inv);
            pn[12]=f2bf(q3.x*inv); pn[13]=f2bf(q3.y*inv); pn[14]=f2bf(q3.z*inv); pn[15]=f2bf(q3.w*inv);
            *(uint4*)(xnb + tc * 16)     = ((uint4*)pn)[0];
            *(uint4*)(xnb + tc * 16 + 8) = ((uint4*)pn)[1];
        }
        float best = -1e30f; int bi = 0;
        const float* rp = rotT + h * 1024;
        for (int i = 0; i < 64; ++i) {
            const float4* r4 = (const float4*)(rp + i * 16);
            float v = dot4(q0, r4[0]) + dot4(q1, r4[1]) + dot4(q2, r4[2]) + dot4(q3, r4[3]);
            if (v > best) { best = v; bi = i; }   // strict > = first max (jnp.argmax)
        }
        codes[(size_t)n * TOT + h * LL + (tc - (size_t)n * LL)] = (unsigned char)(h * 64 + bi);
        return;
    }

    // ================= convbf-conv personality (b = 0..383) ====================
    unsigned short* xt  = (unsigned short*)smem;            // [150][72]  21600 B
    unsigned short* fet = (unsigned short*)(smem + 21600);  // [48][72]    6912 B
    unsigned short* hb  = (unsigned short*)(smem + 28512);  // [48][168]  16128 B
    int b = bq * 4 + (b7 - 3);
    int n = b / 192, rem = b % 192;
    int y = rem >> 1, strip = rem & 1;
    int x0 = strip * 48;
    for (int e = tid; e < 9600; e += 256) {
        int r = e / 3200, r2 = e - r * 3200;
        int c = r2 / 50, j = r2 - c * 50;
        int gy = y - 1 + r, gx = x0 - 1 + j;
        float v = 0.f;
        if ((unsigned)gy < 96u && (unsigned)gx < 96u)
            v = x[((n * 64 + c) * 96 + gy) * 96 + gx];
        xt[(r * 50 + j) * 72 + c] = f2bf(v);
    }
    for (int e = tid; e < 384; e += 256) {       // hb K-pad zero (cols 144..159)
        int r = e >> 3, pq = e & 7;
        *(unsigned int*)(hb + r * 168 + 144 + pq * 2) = 0;
    }
    __syncthreads();
    int wave = tid >> 6, lane = tid & 63;
    int n16 = lane & 15, quad = lane >> 4;
    f32x4 acc[2][3];
    #pragma unroll
    for (int mi = 0; mi < 2; ++mi)
        #pragma unroll
        for (int nt = 0; nt < 3; ++nt) acc[mi][nt] = (f32x4){0.f, 0.f, 0.f, 0.f};
    #pragma unroll
    for (int s = 0; s < 18; ++s) {
        int dydx = s >> 1, half = s & 1;
        int dy = dydx / 3, dxm = dydx - dy * 3;
        bf16x8 B[3];
        #pragma unroll
        for (int nt = 0; nt < 3; ++nt) {
            int j = nt * 16 + n16 + dxm;
            B[nt] = *(bf16x8*)(xt + (dy * 50 + j) * 72 + half * 32 + quad * 8);
        }
        #pragma unroll
        for (int mi = 0; mi < 2; ++mi) {
            int o = (wave * 2 + mi) * 16 + n16;
            bf16x8 A = *(const bf16x8*)(wpack + o * 576 + dydx * 64 + half * 32 + quad * 8);
            #pragma unroll
            for (int nt = 0; nt < 3; ++nt)
                acc[mi][nt] = __builtin_amdgcn_mfma_f32_16x16x32_bf16(A, B[nt], acc[mi][nt], 0, 0, 0);
        }
    }
    #pragma unroll
    for (int mi = 0; mi < 2; ++mi) {
        int mt = wave * 2 + mi;
        int obase = mt * 16 + quad * 4;          // 0..124, multiple of 4
        float4 b4 = (mt < 4) ? *(const float4*)(ba + obase)
                             : *(const float4*)(bfb + obase - 64);
        #pragma unroll
        for (int nt = 0; nt < 3; ++nt) {
            int j = nt * 16 + n16;               // local position 0..47
            unsigned short pk[4];
            float v0 = acc[mi][nt][0] + b4.x; pk[0] = f2bf(v0 > 0.f ? v0 : 0.f);
            float v1 = acc[mi][nt][1] + b4.y; pk[1] = f2bf(v1 > 0.f ? v1 : 0.f);
            float v2 = acc[mi][nt][2] + b4.z; pk[2] = f2bf(v2 > 0.f ? v2 : 0.f);
            float v3 = acc[mi][nt][3] + b4.w; pk[3] = f2bf(v3 > 0.f ? v3 : 0.f);
            if (mt < 4) {
                size_t t = (size_t)n * LL + y * 96 + x0 + j;
                *(uint2*)(yeb + t * 64 + obase) = *(uint2*)pk;
            } else {
                *(uint2*)(fet + j * 72 + (obase - 64)) = *(uint2*)pk;
            }
        }
    }
    __syncthreads();
    size_t R0 = (size_t)n * LL + y * 96 + x0;
    // GEMM1: hid = relu(fe @ w1^T + b1)
    for (int nt = wave; nt < 9; nt += 4) {
        int bn = nt * 16 + n16;
        bf16x8 b0 = *(const bf16x8*)(w1bf + bn * 64 + quad * 8);
        bf16x8 b1 = *(const bf16x8*)(w1bf + bn * 64 + 32 + quad * 8);
        float bb = fc1_b[bn];
        #pragma unroll
        for (int m = 0; m < 3; ++m) {
            int arow = m * 16 + n16;
            bf16x8 a0 = *(bf16x8*)(fet + arow * 72 + quad * 8);
            bf16x8 a1 = *(bf16x8*)(fet + arow * 72 + 32 + quad * 8);
            f32x4 c2 = {0.f, 0.f, 0.f, 0.f};
            c2 = __builtin_amdgcn_mfma_f32_16x16x32_bf16(a0, b0, c2, 0, 0, 0);
            c2 = __builtin_amdgcn_mfma_f32_16x16x32_bf16(a1, b1, c2, 0, 0, 0);
            #pragma unroll
            for (int r = 0; r < 4; ++r) {
                float v = c2[r] + bb;
                hb[(m * 16 + quad * 4 + r) * 168 + bn] = f2bf(v > 0.f ? v : 0.f);
            }
        }
    }
    __syncthreads();
    // GEMM2: re2 = hid @ w2^T + b2 (K=160)
    for (int nt = wave; nt < 9; nt += 4) {
        int bn = nt * 16 + n16;
        bf16x8 wv2[5];
        #pragma unroll
        for (int kk = 0; kk < 5; ++kk)
            wv2[kk] = *(const bf16x8*)(w2bf + bn * 160 + kk * 32 + quad * 8);
        float bb = fc2_b[bn];
        #pragma unroll
        for (int m = 0; m < 3; ++m) {
            int arow = m * 16 + n16;
            f32x4 c2 = {0.f, 0.f, 0.f, 0.f};
            #pragma unroll
            for (int kk = 0; kk < 5; ++kk) {
                bf16x8 a = *(bf16x8*)(hb + arow * 168 + kk * 32 + quad * 8);
                c2 = __builtin_amdgcn_mfma_f32_16x16x32_bf16(a, wv2[kk], c2, 0, 0, 0);
            }
            #pragma unroll
            for (int r = 0; r < 4; ++r)
                re2b[(R0 + m * 16 + quad * 4 + r) * 144 + bn] = f2bf(c2[r] + bb);
        }
    }
}

// ---------------- K1b: histogram (needs codes from k_conv2) ---------------------
__global__ __launch_bounds__(256) void k_hist(
    const unsigned char* __restrict__ codes, int* __restrict__ hist)
{
    __shared__ int lh[256];
    int b2 = blockIdx.x;
    int n = b2 / NSEG, seg = b2 % NSEG;
    int tid = threadIdx.x;
    lh[tid] = 0;
    __syncthreads();
    int code = codes[(size_t)n * TOT + seg * 256 + tid];
    atomicAdd(&lh[code], 1);
    __syncthreads();
    hist[((size_t)n * 256 + tid) * NSEG + seg] = lh[tid];
}

// ---------------- K3: counting sort scan + place --------------------------------
// launch_bounds(256,1) -> int4 buf[36] (144 regs) stays IN REGISTERS.
__global__ __launch_bounds__(256, 1) void k_scan(int* __restrict__ hist)
{
    __shared__ int sc[256];
    int n = blockIdx.x, bin = threadIdx.x;
    int* hp = hist + ((size_t)n * 256 + bin) * NSEG;
    int4 buf[36];
    int4* hp4 = (int4*)hp;
    #pragma unroll
    for (int q = 0; q < 36; ++q) buf[q] = hp4[q];
    int running = 0;
    #pragma unroll
    for (int q = 0; q < 36; ++q) {
        int t0 = buf[q].x; buf[q].x = running; running += t0;
        int t1 = buf[q].y; buf[q].y = running; running += t1;
        int t2 = buf[q].z; buf[q].z = running; running += t2;
        int t3 = buf[q].w; buf[q].w = running; running += t3;
    }
    sc[bin] = running;
    __syncthreads();
    for (int off = 1; off < 256; off <<= 1) {
        int v = sc[bin];
        int u = (bin >= off) ? sc[bin - off] : 0;
        __syncthreads();
        sc[bin] = v + u;
        __syncthreads();
    }
    int bs = sc[bin] - running;   // exclusive prefix over bins
    #pragma unroll
    for (int q = 0; q < 36; ++q) {
        buf[q].x += bs; buf[q].y += bs; buf[q].z += bs; buf[q].w += bs;
        hp4[q] = buf[q];
    }
}

// rank = within-wave serial rank (tid order) + earlier waves' full counts.
__global__ __launch_bounds__(256) void k_place(
    const unsigned char* __restrict__ codes, const int* __restrict__ hist,
    int* __restrict__ idx)
{
    __shared__ unsigned char cl[256];
    __shared__ int wh[4][256];
    int b = blockIdx.x, n = b / NSEG, seg = b % NSEG;
    int tid = threadIdx.x, wv = tid >> 6;
    for (int e = tid; e < 1024; e += 256) ((int*)wh)[e] = 0;
    int my = codes[(size_t)n * TOT + seg * 256 + tid];
    cl[tid] = (unsigned char)my;
    __syncthreads();
    atomicAdd(&wh[wv][my], 1);
    __syncthreads();
    int rank = 0;
    for (int j = wv << 6; j < tid; ++j) rank += (cl[j] == my);
    #pragma unroll
    for (int w = 0; w < 3; ++w)
        if (w < wv) rank += wh[w][my];
    int pos = hist[((size_t)n * 256 + my) * NSEG + seg] + rank;
    idx[(size_t)n * TOT + pos] = seg * 256 + tid;
}

// ---------------- K3b: materialize sorted operand streams -----------------------
// Split personalities (grid 1024): blocks <512 do qs/ks/vsT; >=512 fst + undo.
__global__ __launch_bounds__(256) void k_gather(
    const int* __restrict__ idx, const unsigned short* __restrict__ xeb,
    const unsigned short* __restrict__ xnb, const unsigned short* __restrict__ yeb,
    const unsigned short* __restrict__ re2b,
    unsigned short* __restrict__ qs, unsigned short* __restrict__ ks,
    unsigned short* __restrict__ vsT, unsigned short* __restrict__ fst,
    int* __restrict__ undo)
{
    __shared__ int tl[144];
    int b0 = blockIdx.x;
    int half = b0 >> 9, bb = b0 & 511;
    int b = ((bb & 7) << 6) | (bb >> 3);        // 512 = 8 x 64, bijective
    int nh = b >> 6, chunk = b & 63;
    int n = nh >> 2, h = nh & 3;
    size_t gb = (size_t)nh * LL + chunk * 144;  // sorted-global slot base
    size_t nL = (size_t)n * LL;
    int tid = threadIdx.x;
    if (tid < 144) {
        int t = idx[(size_t)n * TOT + h * LL + chunk * 144 + tid] - h * LL;
        tl[tid] = t;
        if (half) undo[(size_t)nh * LL + t] = chunk * 144 + tid;
    }
    __syncthreads();
    if (!half) {
        // qs/ks: 2x16B per slot
        for (int e = tid; e < 288; e += 256) {
            int s = e >> 1, hf = e & 1;
            size_t src = (nL + tl[s]) * 16 + hf * 8;
            *(uint4*)(qs + (gb + s) * 16 + hf * 8) = *(const uint4*)(xeb + src);
            *(uint4*)(ks + (gb + s) * 16 + hf * 8) = *(const uint4*)(xnb + src);
        }
        // vsT: [c][slot] transposed, slot-pairs packed as u32
        size_t vb = (size_t)(nh * 64 + chunk) * 64;
        for (int e = tid; e < 576; e += 256) {
            int p = e % 72, su = e / 72;         // p = slot pair, su = 8-ch chunk
            uint4 a  = *(const uint4*)(yeb + (nL + tl[2 * p])     * 64 + su * 8);
            uint4 bq = *(const uint4*)(yeb + (nL + tl[2 * p + 1]) * 64 + su * 8);
            const unsigned short* pa = (const unsigned short*)&a;
            const unsigned short* pb = (const unsigned short*)&bq;
            #pragma unroll
            for (int ci = 0; ci < 8; ++ci) {
                int c = su * 8 + ci;
                *(unsigned int*)(vsT + (vb + c) * 144 + 2 * p) =
                    (unsigned int)pa[ci] | ((unsigned int)pb[ci] << 16);
            }
        }
    } else {
        // fst: per-mt slices, 32B contiguous per slot
        for (int e = tid; e < 1296; e += 256) {
            int mt = e / 144, s = e - mt * 144;
            const unsigned short* src = re2b + (nL + tl[s]) * 144 + mt * 16;
            unsigned short* dst = fst + ((size_t)(nh * 9 + mt) * LL + chunk * 144 + s) * 16;
            *(uint4*)(dst)     = *(const uint4*)(src);
            *(uint4*)(dst + 8) = *(const uint4*)(src + 8);
        }
    }
}

// ---------------- K4: bucketed attention — wave-jobs + pipelined, (256,2) -------
// Wave = one (bucket, mt) job, 4 waves/block, grid 1152; dense ks/fst/vsT
// streams (FETCH at cold-miss floor); ping-pong prefetch of next subtile's
// ks+fv; Bv0 hoisted above softmax.
__global__ __launch_bounds__(256, 2) void k_attn(
    const unsigned short* __restrict__ qs, const unsigned short* __restrict__ ks,
    const unsigned short* __restrict__ vsT, const unsigned short* __restrict__ fst,
    unsigned short* __restrict__ rets, float* __restrict__ bscs)
{
    __shared__ __align__(16) unsigned short Pw[4][16 * 56];   // per-wave P (7 KB)

    int B = blockIdx.x;
    int wb = (B & 7) * 144 + (B >> 3);           // XCD x -> jobs of one (n,h)
    int tid = threadIdx.x;
    int lane = tid & 63, wv = tid >> 6;
    int n16 = lane & 15, quad = lane >> 4;
    int job = wb * 4 + wv;                       // 0..4607
    int bucket = job / 9, mt = job - bucket * 9;
    int n = bucket >> 8, rem = bucket & 255;
    int h = rem >> 6, k = rem & 63;
    int nh = n * 4 + h;

    size_t hL = (size_t)nh * LL;
    int ch0 = k, ch1 = (k + 63) & 63, ch2 = (k + 1) & 63;
    unsigned short* Pp = &Pw[wv][0];
    const unsigned short* fsl = fst + (size_t)(nh * 9 + mt) * LL * 16;

    // query A-fragment: K=16 real, padded to 32 via zero quads>=2
    bf16x8 afragQ = {};
    if (quad < 2)
        afragQ = *(const bf16x8*)(qs + (hL + ch0 * 144 + mt * 16 + n16) * 16 + quad * 8);

    f32x4 acc[4];                                // [ct]: channels ct*16+n16
    float rm[4], rl[4];
    #pragma unroll
    for (int ct = 0; ct < 4; ++ct) acc[ct] = (f32x4){0.f, 0.f, 0.f, 0.f};
    #pragma unroll
    for (int r = 0; r < 4; ++r) { rm[r] = -1e30f; rl[r] = 0.f; }

    // chunk-local slot base of subtile T (T = reg*3 + sub)
#define SLOT(T) ((((T) < 3) ? ch0 : ((T) < 6) ? ch1 : ch2) * 144 + ((T) % 3) * 48)

// issue subtile T's chain-head loads (ks for QK B-operand, fv for QK C-init)
#define LOAD_KF(T, KS, FV) do {                                                      \
    int sl_ = SLOT(T);                                                               \
    if (quad < 2) {                                                                  \
        KS[0] = *(const bf16x8*)(ks + (hL + sl_ + n16) * 16 + quad * 8);             \
        KS[1] = *(const bf16x8*)(ks + (hL + sl_ + 16 + n16) * 16 + quad * 8);        \
        KS[2] = *(const bf16x8*)(ks + (hL + sl_ + 32 + n16) * 16 + quad * 8);        \
    }                                                                                \
    FV[0] = *(const ushort4*)(fsl + (size_t)(sl_ + n16) * 16 + quad * 4);            \
    FV[1] = *(const ushort4*)(fsl + (size_t)(sl_ + 16 + n16) * 16 + quad * 4);       \
    FV[2] = *(const ushort4*)(fsl + (size_t)(sl_ + 32 + n16) * 16 + quad * 4);       \
} while (0)

// one subtile: Bv0 early, prefetch next ks/fv, QK (operands pre-loaded),
// softmax, PV (kk1 Bv loads overlap kk0 MFMAs).
#define ATTN_ITER(T, KS, FV, NKS, NFV) do {                                          \
    int chx_ = ((T) < 3) ? ch0 : ((T) < 6) ? ch1 : ch2;                              \
    const unsigned short* vch_ = vsT + (size_t)(nh * 64 + chx_) * 9216;              \
    int vo_ = ((T) % 3) * 48;                                                        \
    bf16x8 Bv0_[4];                                                                  \
    _Pragma("unroll")                                                                \
    for (int ct_ = 0; ct_ < 4; ++ct_)                                                \
        Bv0_[ct_] = *(const bf16x8*)(vch_ + (size_t)(ct_ * 16 + n16) * 144 + vo_ + quad * 8); \
    if ((T) < 8) LOAD_KF((T) + 1, NKS, NFV);                                         \
    f32x4 c0_ = {bf2f(FV[0].x), bf2f(FV[0].y), bf2f(FV[0].z), bf2f(FV[0].w)};        \
    f32x4 c1_ = {bf2f(FV[1].x), bf2f(FV[1].y), bf2f(FV[1].z), bf2f(FV[1].w)};        \
    f32x4 c2_ = {bf2f(FV[2].x), bf2f(FV[2].y), bf2f(FV[2].z), bf2f(FV[2].w)};        \
    c0_ = __builtin_amdgcn_mfma_f32_16x16x32_bf16(afragQ, KS[0], c0_, 0, 0, 0);      \
    c1_ = __builtin_amdgcn_mfma_f32_16x16x32_bf16(afragQ, KS[1], c1_, 0, 0, 0);      \
    c2_ = __builtin_amdgcn_mfma_f32_16x16x32_bf16(afragQ, KS[2], c2_, 0, 0, 0);      \
    _Pragma("unroll")                                                                \
    for (int r_ = 0; r_ < 4; ++r_) {                                                 \
        float v0_ = c0_[r_], v1_ = c1_[r_], v2_ = c2_[r_];                           \
        float mm_ = fmaxf(fmaxf(v0_, v1_), v2_);                                     \
        mm_ = fmaxf(mm_, __shfl_xor(mm_, 1, 16));                                    \
        mm_ = fmaxf(mm_, __shfl_xor(mm_, 2, 16));                                    \
        mm_ = fmaxf(mm_, __shfl_xor(mm_, 4, 16));                                    \
        mm_ = fmaxf(mm_, __shfl_xor(mm_, 8, 16));                                    \
        float mn_ = fmaxf(rm[r_], mm_);                                              \
        float a_ = __expf(rm[r_] - mn_);                                             \
        float s0_ = __expf(v0_ - mn_), s1_ = __expf(v1_ - mn_), s2_ = __expf(v2_ - mn_); \
        float ss_ = s0_ + s1_ + s2_;                                                 \
        ss_ += __shfl_xor(ss_, 1, 16);                                               \
        ss_ += __shfl_xor(ss_, 2, 16);                                               \
        ss_ += __shfl_xor(ss_, 4, 16);                                               \
        ss_ += __shfl_xor(ss_, 8, 16);                                               \
        rl[r_] = rl[r_] * a_ + ss_;                                                  \
        rm[r_] = mn_;                                                                \
        acc[0][r_] *= a_; acc[1][r_] *= a_; acc[2][r_] *= a_; acc[3][r_] *= a_;      \
        int rw_ = quad * 4 + r_;                                                     \
        Pp[rw_ * 56 +      n16] = f2bf(s0_);                                         \
        Pp[rw_ * 56 + 16 + n16] = f2bf(s1_);                                         \
        Pp[rw_ * 56 + 32 + n16] = f2bf(s2_);                                         \
    }                                                                                \
    /* PV kk=0 (Bv0 prefetched); kk=1 Bv loads issued before kk0 MFMAs */            \
    bf16x8 Ap0_ = *(const bf16x8*)(Pp + n16 * 56 + quad * 8);                        \
    int ko1_ = (quad < 2) ? 32 + quad * 8 : 0;  /* clamped: zero P operand */        \
    bf16x8 Bv1_[4];                                                                  \
    _Pragma("unroll")                                                                \
    for (int ct_ = 0; ct_ < 4; ++ct_)                                                \
        Bv1_[ct_] = *(const bf16x8*)(vch_ + (size_t)(ct_ * 16 + n16) * 144 + vo_ + ko1_); \
    _Pragma("unroll")                                                                \
    for (int ct_ = 0; ct_ < 4; ++ct_)                                                \
        acc[ct_] = __builtin_amdgcn_mfma_f32_16x16x32_bf16(Ap0_, Bv0_[ct_], acc[ct_], 0, 0, 0); \
    bf16x8 Ap1_ = {};                                                                \
    if (quad < 2)                                                                    \
        Ap1_ = *(const bf16x8*)(Pp + n16 * 56 + 32 + quad * 8);                      \
    _Pragma("unroll")                                                                \
    for (int ct_ = 0; ct_ < 4; ++ct_)                                                \
        acc[ct_] = __builtin_amdgcn_mfma_f32_16x16x32_bf16(Ap1_, Bv1_[ct_], acc[ct_], 0, 0, 0); \
} while (0)

    bf16x8 ksA[3] = {}, ksB[3] = {};
    ushort4 fvA[3], fvB[3];
    LOAD_KF(0, ksA, fvA);
    ATTN_ITER(0, ksA, fvA, ksB, fvB);
    ATTN_ITER(1, ksB, fvB, ksA, fvA);
    ATTN_ITER(2, ksA, fvA, ksB, fvB);
    ATTN_ITER(3, ksB, fvB, ksA, fvA);
    ATTN_ITER(4, ksA, fvA, ksB, fvB);
    ATTN_ITER(5, ksB, fvB, ksA, fvA);
    ATTN_ITER(6, ksA, fvA, ksB, fvB);
    ATTN_ITER(7, ksB, fvB, ksA, fvA);
    ATTN_ITER(8, ksA, fvA, ksB, fvB);

#undef ATTN_ITER
#undef LOAD_KF
#undef SLOT

    // ---- epilogue: dense writes in sorted order ----
    size_t sp0 = hL + ch0 * 144;
    if (n16 == 0) {
        #pragma unroll
        for (int r = 0; r < 4; ++r)
            bscs[sp0 + mt * 16 + quad * 4 + r] = rm[r] + __logf(rl[r]);
    }
    #pragma unroll
    for (int r = 0; r < 4; ++r) {
        float inv = 1.f / rl[r];
        #pragma unroll
        for (int ct = 0; ct < 4; ++ct)
            rets[(sp0 + mt * 16 + quad * 4 + r) * 64 + ct * 16 + n16] =
                f2bf(acc[ct][r] * inv);
    }
}

// ---------------- K5: softmax over rounds + residual, NCHW output ----------------
// grid 1152 (16 positions per block): 4x wave parallelism on scattered reads.
__global__ __launch_bounds__(256) void k_final(
    const unsigned short* __restrict__ rets, const float* __restrict__ bscs,
    const int* __restrict__ undo, const float* __restrict__ x,
    float* __restrict__ out)
{
    __shared__ float pr[4][16];
    __shared__ int us[4][16];
    __shared__ float accl[64 * 17];
    int b = blockIdx.x, n = b / 576;
    int t0 = (b % 576) * 16;
    int tid = threadIdx.x;
    if (tid < 64) {
        int h = tid >> 4, tt = tid & 15;
        us[h][tt] = undo[((size_t)n * 4 + h) * LL + t0 + tt];
    }
    __syncthreads();
    if (tid < 16) {
        float b0 = bscs[((size_t)n * 4 + 0) * LL + us[0][tid]];
        float b1 = bscs[((size_t)n * 4 + 1) * LL + us[1][tid]];
        float b2 = bscs[((size_t)n * 4 + 2) * LL + us[2][tid]];
        float b3 = bscs[((size_t)n * 4 + 3) * LL + us[3][tid]];
        float mx = fmaxf(fmaxf(b0, b1), fmaxf(b2, b3));
        float e0 = __expf(b0-mx), e1 = __expf(b1-mx), e2 = __expf(b2-mx), e3 = __expf(b3-mx);
        float inv = 1.f / (e0 + e1 + e2 + e3);
        pr[0][tid] = e0*inv; pr[1][tid] = e1*inv; pr[2][tid] = e2*inv; pr[3][tid] = e3*inv;
    }
    __syncthreads();
    int cc = tid & 63, tq = tid >> 6;
    #pragma unroll
    for (int q = 0; q < 4; ++q) {
        int tt = tq * 4 + q;
        float v = 0.f;
        #pragma unroll
        for (int h2 = 0; h2 < 4; ++h2)
            v += bf2f(rets[(((size_t)n*4 + h2)*LL + us[h2][tt])*64 + cc]) * pr[h2][tt];
        accl[cc*17 + tt] = v;
    }
    __syncthreads();
    int tt = tid & 15, c4 = tid >> 4;
    #pragma unroll
    for (int q = 0; q < 4; ++q) {
        int ch = c4 + 16*q;
        size_t o = ((size_t)n*64 + ch)*LL + t0 + tt;
        out[o] = accl[ch*17 + tt] + x[o];   // RES_SCALE = 1.0
    }
}

// ---------------- launcher ----------------
extern "C" void kernel_launch(void* const* d_in, const int* in_sizes, int n_in,
                              void* d_out, int out_size, void* d_ws, size_t ws_size,
                              hipStream_t stream)
{
    const float* x    = (const float*)d_in[0];
    const float* rot  = (const float*)d_in[1];
    const float* wm   = (const float*)d_in[2];
    const float* bm   = (const float*)d_in[3];
    const float* wa   = (const float*)d_in[4];
    const float* ba   = (const float*)d_in[5];
    const float* wf   = (const float*)d_in[6];
    const float* bf   = (const float*)d_in[7];
    const float* fc1w = (const float*)d_in[8];
    const float* fc1b = (const float*)d_in[9];
    const float* fc2w = (const float*)d_in[10];
    const float* fc2b = (const float*)d_in[11];
    float* out = (float*)d_out;

    char* ws = (char*)d_ws;
    // pre-sort stage
    unsigned short* xeb  = (unsigned short*)(ws + 0);         // 2*9216*16 bf16
    unsigned short* yeb  = (unsigned short*)(ws + 589824);    // 2*9216*64 bf16
    unsigned short* xnb  = (unsigned short*)(ws + 2949120);   // 2*9216*16 bf16
    unsigned short* re2b = (unsigned short*)(ws + 3538944);   // 2*9216*144 bf16
    unsigned short* w1bf = (unsigned short*)(ws + 8847360);   // 144*64 bf16
    unsigned short* w2bf = (unsigned short*)(ws + 8865792);   // 144*160 bf16
    unsigned short* wpak = (unsigned short*)(ws + 8911872);   // 128*576 bf16
    unsigned char* codes = (unsigned char*)(ws + 9059328);    // 2*36864 u8
    int* hist            = (int*)(ws + 9133056);              // 2*256*144 i32
    int* idxb            = (int*)(ws + 9427968);              // 2*36864 i32 -> 9,575,424
    // post-sort stage. rets/bscs ALIAS the pre-sort region (xeb..idxb), which is
    // dead once k_gather has run (k_attn reads only qs/ks/vsT/fst).
    unsigned short* rets = (unsigned short*)(ws + 0);         // 8*9216*64 bf16 (9,437,184)
    float* bscs          = (float*)(ws + 9437184);            // 8*9216 f32
    unsigned short* qs   = (unsigned short*)(ws + 9732096);   // 8*9216*16 bf16
    unsigned short* ks   = (unsigned short*)(ws + 12091392);  // 8*9216*16 bf16
    unsigned short* vsT  = (unsigned short*)(ws + 14450688);  // 512*64*144 bf16 (9.4 MB)
    unsigned short* fst  = (unsigned short*)(ws + 23887872);  // 72*9216*16 bf16 (21.2 MB)
    int* undo            = (int*)(ws + 45121536);             // 8*9216 i32 (end 45,416,448)

    k_wprep    <<<288,  256, 0, stream>>>(fc1w, fc2w, wa, wf, w1bf, w2bf, wpak);
    k_conv2    <<<672,  256, 0, stream>>>(x, wm, bm, rot, xeb, xnb, codes,
                                          wpak, ba, bf, w1bf, fc1b, w2bf, fc2b,
                                          yeb, re2b);
    k_hist     <<<288,  256, 0, stream>>>(codes, hist);
    k_scan     <<<2,    256, 0, stream>>>(hist);
    k_place    <<<288,  256, 0, stream>>>(codes, hist, idxb);
    k_gather   <<<1024, 256, 0, stream>>>(idxb, xeb, xnb, yeb, re2b,
                                          qs, ks, vsT, fst, undo);
    k_attn     <<<1152, 256, 0, stream>>>(qs, ks, vsT, fst, rets, bscs);
    k_final    <<<1152, 256, 0, stream>>>(rets, bscs, undo, x, out);
}

// Round 19
// 189.929 us; speedup vs baseline: 1.0061x; 1.0061x over previous
//
#include <hip/hip_runtime.h>
#include <hip/hip_bf16.h>

#define LL 9216            // 96*96
#define TOT 36864          // 4*LL
#define CHK 144
#define NSEG 144
#define EPS_N 5e-5f

typedef __bf16 bf16x8 __attribute__((ext_vector_type(8)));
typedef float f32x4 __attribute__((ext_vector_type(4)));

__device__ __forceinline__ float dot4(float4 a, float4 b) {
    return a.x*b.x + a.y*b.y + a.z*b.z + a.w*b.w;
}
__device__ __forceinline__ unsigned short f2bf(float f) {
    __hip_bfloat16 h = __float2bfloat16(f);
    return *reinterpret_cast<unsigned short*>(&h);
}
__device__ __forceinline__ float bf2f(unsigned short u) {
    return __uint_as_float(((unsigned int)u) << 16);
}

// ---------------- K0: weight prep (extracted so k_conv2 can depend on it) -------
__global__ __launch_bounds__(256) void k_wprep(
    const float* __restrict__ fc1w, const float* __restrict__ fc2w,
    const float* __restrict__ wa, const float* __restrict__ wf,
    unsigned short* __restrict__ w1bf, unsigned short* __restrict__ w2bf,
    unsigned short* __restrict__ wpack)
{
    int i = blockIdx.x * 256 + threadIdx.x;
    if (i < 144 * 64) w1bf[i] = f2bf(fc1w[i]);
    if (i < 144 * 160) {
        int r = i / 160, c = i - r * 160;
        w2bf[i] = (c < 144) ? f2bf(fc2w[r * 144 + c]) : 0;
    }
    if (i < 128 * 576) {
        int o = i / 576, kk = i - o * 576;
        int dydx = kk >> 6, c = kk & 63;
        const float* src = (o < 64) ? wa : wf;
        wpack[i] = f2bf(src[(o & 63) * 576 + c * 9 + dydx]);
    }
}

// ---------------- K1: merged convs — front-conv ∥ convbf-conv --------------------
// FINAL lock-in (verified ~190.5us x5). Hot-loop edits (R13/R14) regressed via
// co-compile codegen perturbation; structural fusion (R16) was net-neutral.
// This source has the proven-good allocation for every kernel.
__global__ __launch_bounds__(256) void k_conv2(
    const float* __restrict__ x, const float* __restrict__ wm,
    const float* __restrict__ bm, const float* __restrict__ rot,
    unsigned short* __restrict__ xeb, unsigned short* __restrict__ xnb,
    unsigned char* __restrict__ codes,
    const unsigned short* __restrict__ wpack,
    const float* __restrict__ ba, const float* __restrict__ bfb,
    const unsigned short* __restrict__ w1bf, const float* __restrict__ fc1_b,
    const unsigned short* __restrict__ w2bf, const float* __restrict__ fc2_b,
    unsigned short* __restrict__ yeb, unsigned short* __restrict__ re2b)
{
    __shared__ __align__(16) char smem[47104];   // union of both layouts
    int tid = threadIdx.x;
    int b7 = blockIdx.x % 7, bq = blockIdx.x / 7;

    if (b7 < 3) {
        // ================= front-conv personality (b = 0..287) =================
        float* xl   = (float*)smem;               // [64][10][10]  25600 B
        float* rotT = (float*)(smem + 25600);     // [256][16]     16384 B
        float* xsp  = (float*)(smem + 41984);     // [64][20]       5120 B
        int b = bq * 3 + b7;
        int n = b / 144, tile = b % 144;
        int ty0 = (tile / 12) * 8, tx0 = (tile % 12) * 8;
        for (int li = tid; li < 6400; li += 256) {
            int c = li / 100, s = li % 100;
            int yy = s / 10, xx = s % 10;
            int gy = ty0 + yy - 1, gx = tx0 + xx - 1;
            float v = 0.f;
            if ((unsigned)gy < 96u && (unsigned)gx < 96u)
                v = x[((n * 64 + c) * 96 + gy) * 96 + gx];
            xl[li] = v;
        }
        for (int e = tid; e < 4096; e += 256) {
            int f = e >> 8, r = e & 255;
            rotT[r * 16 + f] = rot[f * 256 + r];   // rot is (16,4,64)
        }
        __syncthreads();
        int p = tid & 63, og = tid >> 6;
        int row = p >> 3, col = p & 7;
        int ogs = __builtin_amdgcn_readfirstlane(og);   // wave-uniform -> s_load
        const float* wb = wm + (size_t)ogs * 4 * 576;
        float acc0 = 0.f, acc1 = 0.f, acc2 = 0.f, acc3 = 0.f;
        for (int c = 0; c < 64; ++c) {
            float xp[9];
            int base = c * 100 + row * 10 + col;
            #pragma unroll
            for (int dy = 0; dy < 3; ++dy)
                #pragma unroll
                for (int dx = 0; dx < 3; ++dx)
                    xp[dy * 3 + dx] = xl[base + dy * 10 + dx];
            const float* w0 = wb + c * 9;
            #pragma unroll
            for (int u = 0; u < 9; ++u) {
                acc0 += w0[u]        * xp[u];
                acc1 += w0[576 + u]  * xp[u];
                acc2 += w0[1152 + u] * xp[u];
                acc3 += w0[1728 + u] * xp[u];
            }
        }
        int o = ogs * 4;
        float v0 = acc0 + bm[o + 0]; v0 = v0 > 0.f ? v0 : 0.f;
        float v1 = acc1 + bm[o + 1]; v1 = v1 > 0.f ? v1 : 0.f;
        float v2 = acc2 + bm[o + 2]; v2 = v2 > 0.f ? v2 : 0.f;
        float v3 = acc3 + bm[o + 3]; v3 = v3 > 0.f ? v3 : 0.f;
        size_t t = (size_t)n * LL + (ty0 + row) * 96 + tx0 + col;
        unsigned short pk[4] = {f2bf(v0), f2bf(v1), f2bf(v2), f2bf(v3)};
        *(uint2*)(xeb + t * 16 + o) = *(uint2*)pk;
        *(float4*)(xsp + p * 20 + o) = make_float4(v0, v1, v2, v3);
        __syncthreads();
        // ---- codes phase: thread = (pos = tid&63, h = tid>>6) ----
        int pos = tid & 63, h = tid >> 6;
        int prow = pos >> 3, pcol = pos & 7;
        size_t tc = (size_t)n * LL + (ty0 + prow) * 96 + tx0 + pcol;
        float4 q0 = *(float4*)(xsp + pos * 20 + 0);
        float4 q1 = *(float4*)(xsp + pos * 20 + 4);
        float4 q2 = *(float4*)(xsp + pos * 20 + 8);
        float4 q3 = *(float4*)(xsp + pos * 20 + 12);
        if (h == 0) {
            float nn = dot4(q0,q0) + dot4(q1,q1) + dot4(q2,q2) + dot4(q3,q3);
            float s = fmaxf(sqrtf(nn), EPS_N);
            float inv = 1.f / s;
            unsigned short pn[16];
            pn[0]=f2bf(q0.x*inv);  pn[1]=f2bf(q0.y*inv);  pn[2]=f2bf(q0.z*inv);  pn[3]=f2bf(q0.w*inv);
            pn[4]=f2bf(q1.x*inv);  pn[5]=f2bf(q1.y*inv);  pn[6]=f2bf(q1.z*inv);  pn[7]=f2bf(q1.w*inv);
            pn[8]=f2bf(q2.x*inv);  pn[9]=f2bf(q2.y*inv);  pn[10]=f2bf(q2.z*inv); pn[11]=f2bf(q2.w*inv);
            pn[12]=f2bf(q3.x*inv); pn[13]=f2bf(q3.y*inv); pn[14]=f2bf(q3.z*inv); pn[15]=f2bf(q3.w*inv);
            *(uint4*)(xnb + tc * 16)     = ((uint4*)pn)[0];
            *(uint4*)(xnb + tc * 16 + 8) = ((uint4*)pn)[1];
        }
        float best = -1e30f; int bi = 0;
        const float* rp = rotT + h * 1024;
        for (int i = 0; i < 64; ++i) {
            const float4* r4 = (const float4*)(rp + i * 16);
            float v = dot4(q0, r4[0]) + dot4(q1, r4[1]) + dot4(q2, r4[2]) + dot4(q3, r4[3]);
            if (v > best) { best = v; bi = i; }   // strict > = first max (jnp.argmax)
        }
        codes[(size_t)n * TOT + h * LL + (tc - (size_t)n * LL)] = (unsigned char)(h * 64 + bi);
        return;
    }

    // ================= convbf-conv personality (b = 0..383) ====================
    unsigned short* xt  = (unsigned short*)smem;            // [150][72]  21600 B
    unsigned short* fet = (unsigned short*)(smem + 21600);  // [48][72]    6912 B
    unsigned short* hb  = (unsigned short*)(smem + 28512);  // [48][168]  16128 B
    int b = bq * 4 + (b7 - 3);
    int n = b / 192, rem = b % 192;
    int y = rem >> 1, strip = rem & 1;
    int x0 = strip * 48;
    for (int e = tid; e < 9600; e += 256) {
        int r = e / 3200, r2 = e - r * 3200;
        int c = r2 / 50, j = r2 - c * 50;
        int gy = y - 1 + r, gx = x0 - 1 + j;
        float v = 0.f;
        if ((unsigned)gy < 96u && (unsigned)gx < 96u)
            v = x[((n * 64 + c) * 96 + gy) * 96 + gx];
        xt[(r * 50 + j) * 72 + c] = f2bf(v);
    }
    for (int e = tid; e < 384; e += 256) {       // hb K-pad zero (cols 144..159)
        int r = e >> 3, pq = e & 7;
        *(unsigned int*)(hb + r * 168 + 144 + pq * 2) = 0;
    }
    __syncthreads();
    int wave = tid >> 6, lane = tid & 63;
    int n16 = lane & 15, quad = lane >> 4;
    f32x4 acc[2][3];
    #pragma unroll
    for (int mi = 0; mi < 2; ++mi)
        #pragma unroll
        for (int nt = 0; nt < 3; ++nt) acc[mi][nt] = (f32x4){0.f, 0.f, 0.f, 0.f};
    #pragma unroll
    for (int s = 0; s < 18; ++s) {
        int dydx = s >> 1, half = s & 1;
        int dy = dydx / 3, dxm = dydx - dy * 3;
        bf16x8 B[3];
        #pragma unroll
        for (int nt = 0; nt < 3; ++nt) {
            int j = nt * 16 + n16 + dxm;
            B[nt] = *(bf16x8*)(xt + (dy * 50 + j) * 72 + half * 32 + quad * 8);
        }
        #pragma unroll
        for (int mi = 0; mi < 2; ++mi) {
            int o = (wave * 2 + mi) * 16 + n16;
            bf16x8 A = *(const bf16x8*)(wpack + o * 576 + dydx * 64 + half * 32 + quad * 8);
            #pragma unroll
            for (int nt = 0; nt < 3; ++nt)
                acc[mi][nt] = __builtin_amdgcn_mfma_f32_16x16x32_bf16(A, B[nt], acc[mi][nt], 0, 0, 0);
        }
    }
    #pragma unroll
    for (int mi = 0; mi < 2; ++mi) {
        int mt = wave * 2 + mi;
        int obase = mt * 16 + quad * 4;          // 0..124, multiple of 4
        float4 b4 = (mt < 4) ? *(const float4*)(ba + obase)
                             : *(const float4*)(bfb + obase - 64);
        #pragma unroll
        for (int nt = 0; nt < 3; ++nt) {
            int j = nt * 16 + n16;               // local position 0..47
            unsigned short pk[4];
            float v0 = acc[mi][nt][0] + b4.x; pk[0] = f2bf(v0 > 0.f ? v0 : 0.f);
            float v1 = acc[mi][nt][1] + b4.y; pk[1] = f2bf(v1 > 0.f ? v1 : 0.f);
            float v2 = acc[mi][nt][2] + b4.z; pk[2] = f2bf(v2 > 0.f ? v2 : 0.f);
            float v3 = acc[mi][nt][3] + b4.w; pk[3] = f2bf(v3 > 0.f ? v3 : 0.f);
            if (mt < 4) {
                size_t t = (size_t)n * LL + y * 96 + x0 + j;
                *(uint2*)(yeb + t * 64 + obase) = *(uint2*)pk;
            } else {
                *(uint2*)(fet + j * 72 + (obase - 64)) = *(uint2*)pk;
            }
        }
    }
    __syncthreads();
    size_t R0 = (size_t)n * LL + y * 96 + x0;
    // GEMM1: hid = relu(fe @ w1^T + b1)
    for (int nt = wave; nt < 9; nt += 4) {
        int bn = nt * 16 + n16;
        bf16x8 b0 = *(const bf16x8*)(w1bf + bn * 64 + quad * 8);
        bf16x8 b1 = *(const bf16x8*)(w1bf + bn * 64 + 32 + quad * 8);
        float bb = fc1_b[bn];
        #pragma unroll
        for (int m = 0; m < 3; ++m) {
            int arow = m * 16 + n16;
            bf16x8 a0 = *(bf16x8*)(fet + arow * 72 + quad * 8);
            bf16x8 a1 = *(bf16x8*)(fet + arow * 72 + 32 + quad * 8);
            f32x4 c2 = {0.f, 0.f, 0.f, 0.f};
            c2 = __builtin_amdgcn_mfma_f32_16x16x32_bf16(a0, b0, c2, 0, 0, 0);
            c2 = __builtin_amdgcn_mfma_f32_16x16x32_bf16(a1, b1, c2, 0, 0, 0);
            #pragma unroll
            for (int r = 0; r < 4; ++r) {
                float v = c2[r] + bb;
                hb[(m * 16 + quad * 4 + r) * 168 + bn] = f2bf(v > 0.f ? v : 0.f);
            }
        }
    }
    __syncthreads();
    // GEMM2: re2 = hid @ w2^T + b2 (K=160)
    for (int nt = wave; nt < 9; nt += 4) {
        int bn = nt * 16 + n16;
        bf16x8 wv2[5];
        #pragma unroll
        for (int kk = 0; kk < 5; ++kk)
            wv2[kk] = *(const bf16x8*)(w2bf + bn * 160 + kk * 32 + quad * 8);
        float bb = fc2_b[bn];
        #pragma unroll
        for (int m = 0; m < 3; ++m) {
            int arow = m * 16 + n16;
            f32x4 c2 = {0.f, 0.f, 0.f, 0.f};
            #pragma unroll
            for (int kk = 0; kk < 5; ++kk) {
                bf16x8 a = *(bf16x8*)(hb + arow * 168 + kk * 32 + quad * 8);
                c2 = __builtin_amdgcn_mfma_f32_16x16x32_bf16(a, wv2[kk], c2, 0, 0, 0);
            }
            #pragma unroll
            for (int r = 0; r < 4; ++r)
                re2b[(R0 + m * 16 + quad * 4 + r) * 144 + bn] = f2bf(c2[r] + bb);
        }
    }
}

// ---------------- K1b: histogram (needs codes from k_conv2) ---------------------
__global__ __launch_bounds__(256) void k_hist(
    const unsigned char* __restrict__ codes, int* __restrict__ hist)
{
    __shared__ int lh[256];
    int b2 = blockIdx.x;
    int n = b2 / NSEG, seg = b2 % NSEG;
    int tid = threadIdx.x;
    lh[tid] = 0;
    __syncthreads();
    int code = codes[(size_t)n * TOT + seg * 256 + tid];
    atomicAdd(&lh[code], 1);
    __syncthreads();
    hist[((size_t)n * 256 + tid) * NSEG + seg] = lh[tid];
}

// ---------------- K3: counting sort scan + place --------------------------------
// launch_bounds(256,1) -> int4 buf[36] (144 regs) stays IN REGISTERS.
__global__ __launch_bounds__(256, 1) void k_scan(int* __restrict__ hist)
{
    __shared__ int sc[256];
    int n = blockIdx.x, bin = threadIdx.x;
    int* hp = hist + ((size_t)n * 256 + bin) * NSEG;
    int4 buf[36];
    int4* hp4 = (int4*)hp;
    #pragma unroll
    for (int q = 0; q < 36; ++q) buf[q] = hp4[q];
    int running = 0;
    #pragma unroll
    for (int q = 0; q < 36; ++q) {
        int t0 = buf[q].x; buf[q].x = running; running += t0;
        int t1 = buf[q].y; buf[q].y = running; running += t1;
        int t2 = buf[q].z; buf[q].z = running; running += t2;
        int t3 = buf[q].w; buf[q].w = running; running += t3;
    }
    sc[bin] = running;
    __syncthreads();
    for (int off = 1; off < 256; off <<= 1) {
        int v = sc[bin];
        int u = (bin >= off) ? sc[bin - off] : 0;
        __syncthreads();
        sc[bin] = v + u;
        __syncthreads();
    }
    int bs = sc[bin] - running;   // exclusive prefix over bins
    #pragma unroll
    for (int q = 0; q < 36; ++q) {
        buf[q].x += bs; buf[q].y += bs; buf[q].z += bs; buf[q].w += bs;
        hp4[q] = buf[q];
    }
}

// rank = within-wave serial rank (tid order) + earlier waves' full counts.
__global__ __launch_bounds__(256) void k_place(
    const unsigned char* __restrict__ codes, const int* __restrict__ hist,
    int* __restrict__ idx)
{
    __shared__ unsigned char cl[256];
    __shared__ int wh[4][256];
    int b = blockIdx.x, n = b / NSEG, seg = b % NSEG;
    int tid = threadIdx.x, wv = tid >> 6;
    for (int e = tid; e < 1024; e += 256) ((int*)wh)[e] = 0;
    int my = codes[(size_t)n * TOT + seg * 256 + tid];
    cl[tid] = (unsigned char)my;
    __syncthreads();
    atomicAdd(&wh[wv][my], 1);
    __syncthreads();
    int rank = 0;
    for (int j = wv << 6; j < tid; ++j) rank += (cl[j] == my);
    #pragma unroll
    for (int w = 0; w < 3; ++w)
        if (w < wv) rank += wh[w][my];
    int pos = hist[((size_t)n * 256 + my) * NSEG + seg] + rank;
    idx[(size_t)n * TOT + pos] = seg * 256 + tid;
}

// ---------------- K3b: materialize sorted operand streams -----------------------
// Split personalities (grid 1024): blocks <512 do qs/ks/vsT; >=512 fst + undo.
__global__ __launch_bounds__(256) void k_gather(
    const int* __restrict__ idx, const unsigned short* __restrict__ xeb,
    const unsigned short* __restrict__ xnb, const unsigned short* __restrict__ yeb,
    const unsigned short* __restrict__ re2b,
    unsigned short* __restrict__ qs, unsigned short* __restrict__ ks,
    unsigned short* __restrict__ vsT, unsigned short* __restrict__ fst,
    int* __restrict__ undo)
{
    __shared__ int tl[144];
    int b0 = blockIdx.x;
    int half = b0 >> 9, bb = b0 & 511;
    int b = ((bb & 7) << 6) | (bb >> 3);        // 512 = 8 x 64, bijective
    int nh = b >> 6, chunk = b & 63;
    int n = nh >> 2, h = nh & 3;
    size_t gb = (size_t)nh * LL + chunk * 144;  // sorted-global slot base
    size_t nL = (size_t)n * LL;
    int tid = threadIdx.x;
    if (tid < 144) {
        int t = idx[(size_t)n * TOT + h * LL + chunk * 144 + tid] - h * LL;
        tl[tid] = t;
        if (half) undo[(size_t)nh * LL + t] = chunk * 144 + tid;
    }
    __syncthreads();
    if (!half) {
        // qs/ks: 2x16B per slot
        for (int e = tid; e < 288; e += 256) {
            int s = e >> 1, hf = e & 1;
            size_t src = (nL + tl[s]) * 16 + hf * 8;
            *(uint4*)(qs + (gb + s) * 16 + hf * 8) = *(const uint4*)(xeb + src);
            *(uint4*)(ks + (gb + s) * 16 + hf * 8) = *(const uint4*)(xnb + src);
        }
        // vsT: [c][slot] transposed, slot-pairs packed as u32
        size_t vb = (size_t)(nh * 64 + chunk) * 64;
        for (int e = tid; e < 576; e += 256) {
            int p = e % 72, su = e / 72;         // p = slot pair, su = 8-ch chunk
            uint4 a  = *(const uint4*)(yeb + (nL + tl[2 * p])     * 64 + su * 8);
            uint4 bq = *(const uint4*)(yeb + (nL + tl[2 * p + 1]) * 64 + su * 8);
            const unsigned short* pa = (const unsigned short*)&a;
            const unsigned short* pb = (const unsigned short*)&bq;
            #pragma unroll
            for (int ci = 0; ci < 8; ++ci) {
                int c = su * 8 + ci;
                *(unsigned int*)(vsT + (vb + c) * 144 + 2 * p) =
                    (unsigned int)pa[ci] | ((unsigned int)pb[ci] << 16);
            }
        }
    } else {
        // fst: per-mt slices, 32B contiguous per slot
        for (int e = tid; e < 1296; e += 256) {
            int mt = e / 144, s = e - mt * 144;
            const unsigned short* src = re2b + (nL + tl[s]) * 144 + mt * 16;
            unsigned short* dst = fst + ((size_t)(nh * 9 + mt) * LL + chunk * 144 + s) * 16;
            *(uint4*)(dst)     = *(const uint4*)(src);
            *(uint4*)(dst + 8) = *(const uint4*)(src + 8);
        }
    }
}

// ---------------- K4: bucketed attention — wave-jobs + pipelined, (256,2) -------
// Wave = one (bucket, mt) job, 4 waves/block, grid 1152; dense ks/fst/vsT
// streams (FETCH at cold-miss floor); ping-pong prefetch of next subtile's
// ks+fv; Bv0 hoisted above softmax.
__global__ __launch_bounds__(256, 2) void k_attn(
    const unsigned short* __restrict__ qs, const unsigned short* __restrict__ ks,
    const unsigned short* __restrict__ vsT, const unsigned short* __restrict__ fst,
    unsigned short* __restrict__ rets, float* __restrict__ bscs)
{
    __shared__ __align__(16) unsigned short Pw[4][16 * 56];   // per-wave P (7 KB)

    int B = blockIdx.x;
    int wb = (B & 7) * 144 + (B >> 3);           // XCD x -> jobs of one (n,h)
    int tid = threadIdx.x;
    int lane = tid & 63, wv = tid >> 6;
    int n16 = lane & 15, quad = lane >> 4;
    int job = wb * 4 + wv;                       // 0..4607
    int bucket = job / 9, mt = job - bucket * 9;
    int n = bucket >> 8, rem = bucket & 255;
    int h = rem >> 6, k = rem & 63;
    int nh = n * 4 + h;

    size_t hL = (size_t)nh * LL;
    int ch0 = k, ch1 = (k + 63) & 63, ch2 = (k + 1) & 63;
    unsigned short* Pp = &Pw[wv][0];
    const unsigned short* fsl = fst + (size_t)(nh * 9 + mt) * LL * 16;

    // query A-fragment: K=16 real, padded to 32 via zero quads>=2
    bf16x8 afragQ = {};
    if (quad < 2)
        afragQ = *(const bf16x8*)(qs + (hL + ch0 * 144 + mt * 16 + n16) * 16 + quad * 8);

    f32x4 acc[4];                                // [ct]: channels ct*16+n16
    float rm[4], rl[4];
    #pragma unroll
    for (int ct = 0; ct < 4; ++ct) acc[ct] = (f32x4){0.f, 0.f, 0.f, 0.f};
    #pragma unroll
    for (int r = 0; r < 4; ++r) { rm[r] = -1e30f; rl[r] = 0.f; }

    // chunk-local slot base of subtile T (T = reg*3 + sub)
#define SLOT(T) ((((T) < 3) ? ch0 : ((T) < 6) ? ch1 : ch2) * 144 + ((T) % 3) * 48)

// issue subtile T's chain-head loads (ks for QK B-operand, fv for QK C-init)
#define LOAD_KF(T, KS, FV) do {                                                      \
    int sl_ = SLOT(T);                                                               \
    if (quad < 2) {                                                                  \
        KS[0] = *(const bf16x8*)(ks + (hL + sl_ + n16) * 16 + quad * 8);             \
        KS[1] = *(const bf16x8*)(ks + (hL + sl_ + 16 + n16) * 16 + quad * 8);        \
        KS[2] = *(const bf16x8*)(ks + (hL + sl_ + 32 + n16) * 16 + quad * 8);        \
    }                                                                                \
    FV[0] = *(const ushort4*)(fsl + (size_t)(sl_ + n16) * 16 + quad * 4);            \
    FV[1] = *(const ushort4*)(fsl + (size_t)(sl_ + 16 + n16) * 16 + quad * 4);       \
    FV[2] = *(const ushort4*)(fsl + (size_t)(sl_ + 32 + n16) * 16 + quad * 4);       \
} while (0)

// one subtile: Bv0 early, prefetch next ks/fv, QK (operands pre-loaded),
// softmax, PV (kk1 Bv loads overlap kk0 MFMAs).
#define ATTN_ITER(T, KS, FV, NKS, NFV) do {                                          \
    int chx_ = ((T) < 3) ? ch0 : ((T) < 6) ? ch1 : ch2;                              \
    const unsigned short* vch_ = vsT + (size_t)(nh * 64 + chx_) * 9216;              \
    int vo_ = ((T) % 3) * 48;                                                        \
    bf16x8 Bv0_[4];                                                                  \
    _Pragma("unroll")                                                                \
    for (int ct_ = 0; ct_ < 4; ++ct_)                                                \
        Bv0_[ct_] = *(const bf16x8*)(vch_ + (size_t)(ct_ * 16 + n16) * 144 + vo_ + quad * 8); \
    if ((T) < 8) LOAD_KF((T) + 1, NKS, NFV);                                         \
    f32x4 c0_ = {bf2f(FV[0].x), bf2f(FV[0].y), bf2f(FV[0].z), bf2f(FV[0].w)};        \
    f32x4 c1_ = {bf2f(FV[1].x), bf2f(FV[1].y), bf2f(FV[1].z), bf2f(FV[1].w)};        \
    f32x4 c2_ = {bf2f(FV[2].x), bf2f(FV[2].y), bf2f(FV[2].z), bf2f(FV[2].w)};        \
    c0_ = __builtin_amdgcn_mfma_f32_16x16x32_bf16(afragQ, KS[0], c0_, 0, 0, 0);      \
    c1_ = __builtin_amdgcn_mfma_f32_16x16x32_bf16(afragQ, KS[1], c1_, 0, 0, 0);      \
    c2_ = __builtin_amdgcn_mfma_f32_16x16x32_bf16(afragQ, KS[2], c2_, 0, 0, 0);      \
    _Pragma("unroll")                                                                \
    for (int r_ = 0; r_ < 4; ++r_) {                                                 \
        float v0_ = c0_[r_], v1_ = c1_[r_], v2_ = c2_[r_];                           \
        float mm_ = fmaxf(fmaxf(v0_, v1_), v2_);                                     \
        mm_ = fmaxf(mm_, __shfl_xor(mm_, 1, 16));                                    \
        mm_ = fmaxf(mm_, __shfl_xor(mm_, 2, 16));                                    \
        mm_ = fmaxf(mm_, __shfl_xor(mm_, 4, 16));                                    \
        mm_ = fmaxf(mm_, __shfl_xor(mm_, 8, 16));                                    \
        float mn_ = fmaxf(rm[r_], mm_);                                              \
        float a_ = __expf(rm[r_] - mn_);                                             \
        float s0_ = __expf(v0_ - mn_), s1_ = __expf(v1_ - mn_), s2_ = __expf(v2_ - mn_); \
        float ss_ = s0_ + s1_ + s2_;                                                 \
        ss_ += __shfl_xor(ss_, 1, 16);                                               \
        ss_ += __shfl_xor(ss_, 2, 16);                                               \
        ss_ += __shfl_xor(ss_, 4, 16);                                               \
        ss_ += __shfl_xor(ss_, 8, 16);                                               \
        rl[r_] = rl[r_] * a_ + ss_;                                                  \
        rm[r_] = mn_;                                                                \
        acc[0][r_] *= a_; acc[1][r_] *= a_; acc[2][r_] *= a_; acc[3][r_] *= a_;      \
        int rw_ = quad * 4 + r_;                                                     \
        Pp[rw_ * 56 +      n16] = f2bf(s0_);                                         \
        Pp[rw_ * 56 + 16 + n16] = f2bf(s1_);                                         \
        Pp[rw_ * 56 + 32 + n16] = f2bf(s2_);                                         \
    }                                                                                \
    /* PV kk=0 (Bv0 prefetched); kk=1 Bv loads issued before kk0 MFMAs */            \
    bf16x8 Ap0_ = *(const bf16x8*)(Pp + n16 * 56 + quad * 8);                        \
    int ko1_ = (quad < 2) ? 32 + quad * 8 : 0;  /* clamped: zero P operand */        \
    bf16x8 Bv1_[4];                                                                  \
    _Pragma("unroll")                                                                \
    for (int ct_ = 0; ct_ < 4; ++ct_)                                                \
        Bv1_[ct_] = *(const bf16x8*)(vch_ + (size_t)(ct_ * 16 + n16) * 144 + vo_ + ko1_); \
    _Pragma("unroll")                                                                \
    for (int ct_ = 0; ct_ < 4; ++ct_)                                                \
        acc[ct_] = __builtin_amdgcn_mfma_f32_16x16x32_bf16(Ap0_, Bv0_[ct_], acc[ct_], 0, 0, 0); \
    bf16x8 Ap1_ = {};                                                                \
    if (quad < 2)                                                                    \
        Ap1_ = *(const bf16x8*)(Pp + n16 * 56 + 32 + quad * 8);                      \
    _Pragma("unroll")                                                                \
    for (int ct_ = 0; ct_ < 4; ++ct_)                                                \
        acc[ct_] = __builtin_amdgcn_mfma_f32_16x16x32_bf16(Ap1_, Bv1_[ct_], acc[ct_], 0, 0, 0); \
} while (0)

    bf16x8 ksA[3] = {}, ksB[3] = {};
    ushort4 fvA[3], fvB[3];
    LOAD_KF(0, ksA, fvA);
    ATTN_ITER(0, ksA, fvA, ksB, fvB);
    ATTN_ITER(1, ksB, fvB, ksA, fvA);
    ATTN_ITER(2, ksA, fvA, ksB, fvB);
    ATTN_ITER(3, ksB, fvB, ksA, fvA);
    ATTN_ITER(4, ksA, fvA, ksB, fvB);
    ATTN_ITER(5, ksB, fvB, ksA, fvA);
    ATTN_ITER(6, ksA, fvA, ksB, fvB);
    ATTN_ITER(7, ksB, fvB, ksA, fvA);
    ATTN_ITER(8, ksA, fvA, ksB, fvB);

#undef ATTN_ITER
#undef LOAD_KF
#undef SLOT

    // ---- epilogue: dense writes in sorted order ----
    size_t sp0 = hL + ch0 * 144;
    if (n16 == 0) {
        #pragma unroll
        for (int r = 0; r < 4; ++r)
            bscs[sp0 + mt * 16 + quad * 4 + r] = rm[r] + __logf(rl[r]);
    }
    #pragma unroll
    for (int r = 0; r < 4; ++r) {
        float inv = 1.f / rl[r];
        #pragma unroll
        for (int ct = 0; ct < 4; ++ct)
            rets[(sp0 + mt * 16 + quad * 4 + r) * 64 + ct * 16 + n16] =
                f2bf(acc[ct][r] * inv);
    }
}

// ---------------- K5: softmax over rounds + residual, NCHW output ----------------
// grid 1152 (16 positions per block): 4x wave parallelism on scattered reads.
__global__ __launch_bounds__(256) void k_final(
    const unsigned short* __restrict__ rets, const float* __restrict__ bscs,
    const int* __restrict__ undo, const float* __restrict__ x,
    float* __restrict__ out)
{
    __shared__ float pr[4][16];
    __shared__ int us[4][16];
    __shared__ float accl[64 * 17];
    int b = blockIdx.x, n = b / 576;
    int t0 = (b % 576) * 16;
    int tid = threadIdx.x;
    if (tid < 64) {
        int h = tid >> 4, tt = tid & 15;
        us[h][tt] = undo[((size_t)n * 4 + h) * LL + t0 + tt];
    }
    __syncthreads();
    if (tid < 16) {
        float b0 = bscs[((size_t)n * 4 + 0) * LL + us[0][tid]];
        float b1 = bscs[((size_t)n * 4 + 1) * LL + us[1][tid]];
        float b2 = bscs[((size_t)n * 4 + 2) * LL + us[2][tid]];
        float b3 = bscs[((size_t)n * 4 + 3) * LL + us[3][tid]];
        float mx = fmaxf(fmaxf(b0, b1), fmaxf(b2, b3));
        float e0 = __expf(b0-mx), e1 = __expf(b1-mx), e2 = __expf(b2-mx), e3 = __expf(b3-mx);
        float inv = 1.f / (e0 + e1 + e2 + e3);
        pr[0][tid] = e0*inv; pr[1][tid] = e1*inv; pr[2][tid] = e2*inv; pr[3][tid] = e3*inv;
    }
    __syncthreads();
    int cc = tid & 63, tq = tid >> 6;
    #pragma unroll
    for (int q = 0; q < 4; ++q) {
        int tt = tq * 4 + q;
        float v = 0.f;
        #pragma unroll
        for (int h2 = 0; h2 < 4; ++h2)
            v += bf2f(rets[(((size_t)n*4 + h2)*LL + us[h2][tt])*64 + cc]) * pr[h2][tt];
        accl[cc*17 + tt] = v;
    }
    __syncthreads();
    int tt = tid & 15, c4 = tid >> 4;
    #pragma unroll
    for (int q = 0; q < 4; ++q) {
        int ch = c4 + 16*q;
        size_t o = ((size_t)n*64 + ch)*LL + t0 + tt;
        out[o] = accl[ch*17 + tt] + x[o];   // RES_SCALE = 1.0
    }
}

// ---------------- launcher ----------------
extern "C" void kernel_launch(void* const* d_in, const int* in_sizes, int n_in,
                              void* d_out, int out_size, void* d_ws, size_t ws_size,
                              hipStream_t stream)
{
    const float* x    = (const float*)d_in[0];
    const float* rot  = (const float*)d_in[1];
    const float* wm   = (const float*)d_in[2];
    const float* bm   = (const float*)d_in[3];
    const float* wa   = (const float*)d_in[4];
    const float* ba   = (const float*)d_in[5];
    const float* wf   = (const float*)d_in[6];
    const float* bf   = (const float*)d_in[7];
    const float* fc1w = (const float*)d_in[8];
    const float* fc1b = (const float*)d_in[9];
    const float* fc2w = (const float*)d_in[10];
    const float* fc2b = (const float*)d_in[11];
    float* out = (float*)d_out;

    char* ws = (char*)d_ws;
    // pre-sort stage
    unsigned short* xeb  = (unsigned short*)(ws + 0);         // 2*9216*16 bf16
    unsigned short* yeb  = (unsigned short*)(ws + 589824);    // 2*9216*64 bf16
    unsigned short* xnb  = (unsigned short*)(ws + 2949120);   // 2*9216*16 bf16
    unsigned short* re2b = (unsigned short*)(ws + 3538944);   // 2*9216*144 bf16
    unsigned short* w1bf = (unsigned short*)(ws + 8847360);   // 144*64 bf16
    unsigned short* w2bf = (unsigned short*)(ws + 8865792);   // 144*160 bf16
    unsigned short* wpak = (unsigned short*)(ws + 8911872);   // 128*576 bf16
    unsigned char* codes = (unsigned char*)(ws + 9059328);    // 2*36864 u8
    int* hist            = (int*)(ws + 9133056);              // 2*256*144 i32
    int* idxb            = (int*)(ws + 9427968);              // 2*36864 i32 -> 9,575,424
    // post-sort stage. rets/bscs ALIAS the pre-sort region (xeb..idxb), which is
    // dead once k_gather has run (k_attn reads only qs/ks/vsT/fst).
    unsigned short* rets = (unsigned short*)(ws + 0);         // 8*9216*64 bf16 (9,437,184)
    float* bscs          = (float*)(ws + 9437184);            // 8*9216 f32
    unsigned short* qs   = (unsigned short*)(ws + 9732096);   // 8*9216*16 bf16
    unsigned short* ks   = (unsigned short*)(ws + 12091392);  // 8*9216*16 bf16
    unsigned short* vsT  = (unsigned short*)(ws + 14450688);  // 512*64*144 bf16 (9.4 MB)
    unsigned short* fst  = (unsigned short*)(ws + 23887872);  // 72*9216*16 bf16 (21.2 MB)
    int* undo            = (int*)(ws + 45121536);             // 8*9216 i32 (end 45,416,448)

    k_wprep    <<<288,  256, 0, stream>>>(fc1w, fc2w, wa, wf, w1bf, w2bf, wpak);
    k_conv2    <<<672,  256, 0, stream>>>(x, wm, bm, rot, xeb, xnb, codes,
                                          wpak, ba, bf, w1bf, fc1b, w2bf, fc2b,
                                          yeb, re2b);
    k_hist     <<<288,  256, 0, stream>>>(codes, hist);
    k_scan     <<<2,    256, 0, stream>>>(hist);
    k_place    <<<288,  256, 0, stream>>>(codes, hist, idxb);
    k_gather   <<<1024, 256, 0, stream>>>(idxb, xeb, xnb, yeb, re2b,
                                          qs, ks, vsT, fst, undo);
    k_attn     <<<1152, 256, 0, stream>>>(qs, ks, vsT, fst, rets, bscs);
    k_final    <<<1152, 256, 0, stream>>>(rets, bscs, undo, x, out);
}